// Round 8
// baseline (149.204 us; speedup 1.0000x reference)
//
#include <hip/hip_runtime.h>

#define N_NODES 100000
#define N_EDGES 1600000
#define DIM 128

#define BSHIFT 8
#define BNODES 256
#define NBUCK 391     // ceil(100000/256)
#define BCAP  4608    // padded bucket capacity (mean 4096, sigma 64, +8 sigma)
#define PCHUNK 4096   // edges per part block
#define NB_PART ((N_EDGES + PCHUNK - 1) / PCHUNK)  // 391

#define GTILES 1563   // ceil(100000/64)
#define GGRID  782

typedef short s16x8 __attribute__((ext_vector_type(8)));
typedef float f32x4 __attribute__((ext_vector_type(4)));

__device__ __forceinline__ unsigned short f2bf(float f) {
    unsigned u = __float_as_uint(f);
    u += 0x7fffu + ((u >> 16) & 1u);   // RNE
    return (unsigned short)(u >> 16);
}
__device__ __forceinline__ float bflo(unsigned u) { return __uint_as_float(u << 16); }
__device__ __forceinline__ float bfhi(unsigned u) { return __uint_as_float(u & 0xffff0000u); }

__device__ __forceinline__ void acc8(float (&a)[8], uint4 v, float w) {
    a[0] = fmaf(bflo(v.x), w, a[0]); a[1] = fmaf(bfhi(v.x), w, a[1]);
    a[2] = fmaf(bflo(v.y), w, a[2]); a[3] = fmaf(bfhi(v.y), w, a[3]);
    a[4] = fmaf(bflo(v.z), w, a[4]); a[5] = fmaf(bfhi(v.z), w, a[5]);
    a[6] = fmaf(bflo(v.w), w, a[6]); a[7] = fmaf(bfhi(v.w), w, a[7]);
}

// ---------------- CSR build (padded buckets) ----------------

__global__ void k_zero(int* __restrict__ gcur) {
    int t = blockIdx.x * blockDim.x + threadIdx.x;
    if (t < NBUCK) gcur[t] = t * BCAP;
}

// ---- partition body ----
__device__ __forceinline__ void part_body(char* smem, int bid,
                                          const int* __restrict__ src,
                                          const int* __restrict__ dst,
                                          int* __restrict__ gcur,
                                          int2* __restrict__ ebuf) {
    int* hist = (int*)smem;
    int* gbase = hist + NBUCK;
    int tid = threadIdx.x;
    long e0 = (long)bid * PCHUNK;
    int n = min(PCHUNK, (int)(N_EDGES - e0));
    for (int b = tid; b < NBUCK; b += 256) hist[b] = 0;
    __syncthreads();

    int mys[16], myd[16];
#pragma unroll
    for (int k = 0; k < 16; ++k) {
        int idx = k * 256 + tid;
        if (idx < n) {
            mys[k] = src[e0 + idx];
            myd[k] = dst[e0 + idx];
            atomicAdd(&hist[myd[k] >> BSHIFT], 1);
        } else {
            myd[k] = -1;
        }
    }
    __syncthreads();
    for (int b = tid; b < NBUCK; b += 256) {
        gbase[b] = hist[b] ? atomicAdd(&gcur[b], hist[b]) : 0;
        hist[b] = 0;  // becomes local cursor
    }
    __syncthreads();
#pragma unroll
    for (int k = 0; k < 16; ++k) {
        if (myd[k] >= 0) {
            int b = myd[k] >> BSHIFT;
            int slot = gbase[b] + atomicAdd(&hist[b], 1);
            ebuf[slot] = make_int2(mys[k], myd[k]);
        }
    }
}

// ---- GEMM body: h1(bf16) = x @ W1, bf16 MFMA, swizzled LDS ----
__device__ __forceinline__ void gemm_body(char* smem, int bid,
                                          const float* __restrict__ x,
                                          const float* __restrict__ W1,
                                          unsigned short* __restrict__ h1) {
    unsigned short* Wt = (unsigned short*)smem;           // 32 KB
    int tid = threadIdx.x;
    for (int idx = tid; idx < DIM * DIM; idx += 256) {
        int k = idx >> 7, c = idx & 127;
        Wt[c * 128 + (k ^ ((c & 7) << 3))] = f2bf(W1[idx]);
    }
    __syncthreads();

    int wv = tid >> 6, lane = tid & 63;
    int g = lane >> 4, tl = lane & 15;
    unsigned short* cst = (unsigned short*)(smem + 32768 + wv * 4096);

    for (int tile = bid; tile < GTILES; tile += GGRID) {
        int rb = tile * 64 + wv * 16;
        if (rb >= N_NODES) continue;

        s16x8 afrag[4];
        const float* xrow = x + (size_t)(rb + tl) * DIM + g * 8;
#pragma unroll
        for (int kc = 0; kc < 4; ++kc) {
            float4 p0 = *(const float4*)(xrow + kc * 32);
            float4 p1 = *(const float4*)(xrow + kc * 32 + 4);
            s16x8 a;
            a[0] = (short)f2bf(p0.x); a[1] = (short)f2bf(p0.y);
            a[2] = (short)f2bf(p0.z); a[3] = (short)f2bf(p0.w);
            a[4] = (short)f2bf(p1.x); a[5] = (short)f2bf(p1.y);
            a[6] = (short)f2bf(p1.z); a[7] = (short)f2bf(p1.w);
            afrag[kc] = a;
        }

        f32x4 acc[8];
#pragma unroll
        for (int ct = 0; ct < 8; ++ct) acc[ct] = (f32x4)0.0f;
#pragma unroll
        for (int kc = 0; kc < 4; ++kc) {
#pragma unroll
            for (int ct = 0; ct < 8; ++ct) {
                int crow = ct * 16 + tl;
                int boff = crow * 256 + ((kc * 64 + g * 16) ^ ((crow & 7) << 4));
                s16x8 b = *(const s16x8*)((const char*)Wt + boff);
                acc[ct] = __builtin_amdgcn_mfma_f32_16x16x32_bf16(afrag[kc], b, acc[ct], 0, 0, 0);
            }
        }

#pragma unroll
        for (int ct = 0; ct < 8; ++ct) {
#pragma unroll
            for (int r = 0; r < 4; ++r) {
                float own = acc[ct][r];
                float oth = __shfl_xor(own, 1, 64);
                if ((lane & 1) == 0) {
                    unsigned pk = (unsigned)f2bf(own) | ((unsigned)f2bf(oth) << 16);
                    int row = g * 4 + r;
                    int col = ct * 16 + tl;
                    *(unsigned*)&cst[row * 128 + (col ^ (row << 3))] = pk;
                }
            }
        }
        asm volatile("s_waitcnt lgkmcnt(0)" ::: "memory");

        unsigned short* dstp = h1 + (size_t)rb * DIM;
#pragma unroll
        for (int c = 0; c < 4; ++c) {
            int row = c * 4 + g;
            uint4 v = *(const uint4*)&cst[row * 128 + ((tl ^ row) * 8)];
            *(uint4*)(dstp + c * 512 + lane * 8) = v;
        }
    }
}

// standalone kernels (fallback path when ws is tight)
__global__ __launch_bounds__(256) void k_part(const int* __restrict__ src,
                                              const int* __restrict__ dst,
                                              int* __restrict__ gcur,
                                              int2* __restrict__ ebuf) {
    __shared__ __align__(16) char smem[2 * NBUCK * 4 + 16];
    part_body(smem, blockIdx.x, src, dst, gcur, ebuf);
}

__global__ __launch_bounds__(256) void k_gemm(const float* __restrict__ x,
                                              const float* __restrict__ W1,
                                              unsigned short* __restrict__ h1) {
    __shared__ __align__(16) char smem[49152];
    gemm_body(smem, blockIdx.x, x, W1, h1);
}

// fused: blocks [0,NB_PART) partition edges, rest do the GEMM
__global__ __launch_bounds__(256) void k_pg(const int* __restrict__ src,
                                            const int* __restrict__ dst,
                                            int* __restrict__ gcur,
                                            int2* __restrict__ ebuf,
                                            const float* __restrict__ x,
                                            const float* __restrict__ W1,
                                            unsigned short* __restrict__ h1) {
    __shared__ __align__(16) char smem[49152];
    if (blockIdx.x < NB_PART) part_body(smem, blockIdx.x, src, dst, gcur, ebuf);
    else                      gemm_body(smem, blockIdx.x - NB_PART, x, W1, h1);
}

// per-bucket degree count + scan -> rp, cnt, dinv (256 nodes/block)
__global__ __launch_bounds__(256) void k_csrA(const int2* __restrict__ ebuf,
                                              const int* __restrict__ gcur,
                                              int* __restrict__ rp,
                                              int* __restrict__ cnt,
                                              float* __restrict__ dinv) {
    __shared__ int lcnt[BNODES];
    __shared__ int psum[BNODES];
    int b = blockIdx.x, t = threadIdx.x;
    int node0 = b << BSHIFT;
    lcnt[t] = 0;
    __syncthreads();
    int base = b * BCAP, end = gcur[b];
    for (int e = base + t; e < end; e += 256)
        atomicAdd(&lcnt[ebuf[e].y - node0], 1);
    __syncthreads();
    int c = lcnt[t];
    psum[t] = c;
    __syncthreads();
    for (int s = 1; s < 256; s <<= 1) {
        int u = (t >= s) ? psum[t - s] : 0;
        __syncthreads();
        psum[t] += u;
        __syncthreads();
    }
    int node = node0 + t;
    if (node < N_NODES) {
        rp[node] = base + psum[t] - c;
        cnt[node] = c;
        dinv[node] = rsqrtf((float)(c + 1));
    }
}

// per-bucket CSR emit with LDS cursors
__global__ __launch_bounds__(256) void k_csrB(const int2* __restrict__ ebuf,
                                              const int* __restrict__ gcur,
                                              const int* __restrict__ rp,
                                              const float* __restrict__ dinv,
                                              int2* __restrict__ csrw) {
    __shared__ int lcur[BNODES];
    __shared__ float ldv[BNODES];
    int b = blockIdx.x, t = threadIdx.x;
    int node0 = b << BSHIFT;
    int base = b * BCAP, end = gcur[b];
    int node = node0 + t;
    if (node < N_NODES) { lcur[t] = rp[node] - base; ldv[t] = dinv[node]; }
    __syncthreads();
    int e = base + t;
    for (; e + 256 < end; e += 512) {
        int2 d0 = ebuf[e];
        int2 d1 = ebuf[e + 256];
        int l0 = d0.y - node0, l1 = d1.y - node0;
        float w0 = dinv[d0.x] * ldv[l0];
        float w1 = dinv[d1.x] * ldv[l1];
        int p0 = atomicAdd(&lcur[l0], 1);
        int p1 = atomicAdd(&lcur[l1], 1);
        csrw[base + p0] = make_int2(d0.x, __float_as_int(w0));
        csrw[base + p1] = make_int2(d1.x, __float_as_int(w1));
    }
    if (e < end) {
        int2 d0 = ebuf[e];
        int l0 = d0.y - node0;
        float w0 = dinv[d0.x] * ldv[l0];
        int p0 = atomicAdd(&lcur[l0], 1);
        csrw[base + p0] = make_int2(d0.x, __float_as_int(w0));
    }
}

// ---------------- agg1 + b1 + ReLU + (r @ W2) -> z[N] ----------------
// 16-lane group per node; 6-edge batches: 3 x uint4 meta (16B-aligned) ->
// 6 independent 256B gathers in flight -> 48 FMAs. VGPR kept < 64 cliff.

__global__ __launch_bounds__(256) void k_agg1(const unsigned short* __restrict__ h1,
                                              const float* __restrict__ dinv,
                                              const int* __restrict__ rp,
                                              const int* __restrict__ cnt,
                                              const int2* __restrict__ csrw,
                                              const float* __restrict__ b1,
                                              const float* __restrict__ W2,
                                              float* __restrict__ z) {
    int lane = threadIdx.x & 63;
    int wv = threadIdx.x >> 6;
    int g = lane >> 4, tl = lane & 15;
    int i = blockIdx.x * 16 + wv * 4 + g;
    int c0 = tl * 8;
    float di = dinv[i];
    int beg = rp[i], end = beg + cnt[i];
    float a[8];
#pragma unroll
    for (int q = 0; q < 8; ++q) a[q] = 0.f;
    const unsigned short* hbase = h1 + c0;

    int j = beg;
    if ((j & 1) && j < end) {  // align to 16B for uint4 meta loads
        int2 e0 = csrw[j];
        uint4 v0 = *(const uint4*)(hbase + (size_t)e0.x * DIM);
        acc8(a, v0, __int_as_float(e0.y));
        ++j;
    }
    for (; j + 6 <= end; j += 6) {
        uint4 m0 = *(const uint4*)(csrw + j);      // edges j, j+1
        uint4 m1 = *(const uint4*)(csrw + j + 2);
        uint4 m2 = *(const uint4*)(csrw + j + 4);
        uint4 v0 = *(const uint4*)(hbase + (size_t)(int)m0.x * DIM);
        uint4 v1 = *(const uint4*)(hbase + (size_t)(int)m0.z * DIM);
        uint4 v2 = *(const uint4*)(hbase + (size_t)(int)m1.x * DIM);
        uint4 v3 = *(const uint4*)(hbase + (size_t)(int)m1.z * DIM);
        uint4 v4 = *(const uint4*)(hbase + (size_t)(int)m2.x * DIM);
        uint4 v5 = *(const uint4*)(hbase + (size_t)(int)m2.z * DIM);
        acc8(a, v0, __int_as_float(m0.y));
        acc8(a, v1, __int_as_float(m0.w));
        acc8(a, v2, __int_as_float(m1.y));
        acc8(a, v3, __int_as_float(m1.w));
        acc8(a, v4, __int_as_float(m2.y));
        acc8(a, v5, __int_as_float(m2.w));
    }
    for (; j < end; ++j) {
        int2 e0 = csrw[j];
        uint4 v0 = *(const uint4*)(hbase + (size_t)e0.x * DIM);
        acc8(a, v0, __int_as_float(e0.y));
    }

    uint4 vs = *(const uint4*)(hbase + (size_t)i * DIM);
    float sii = di * di;
    float4 bA = *(const float4*)(b1 + c0);
    float4 bB = *(const float4*)(b1 + c0 + 4);
    float4 wA = *(const float4*)(W2 + c0);
    float4 wB = *(const float4*)(W2 + c0 + 4);
    float p = 0.f;
    p += fmaxf(fmaf(bflo(vs.x), sii, a[0]) + bA.x, 0.f) * wA.x;
    p += fmaxf(fmaf(bfhi(vs.x), sii, a[1]) + bA.y, 0.f) * wA.y;
    p += fmaxf(fmaf(bflo(vs.y), sii, a[2]) + bA.z, 0.f) * wA.z;
    p += fmaxf(fmaf(bfhi(vs.y), sii, a[3]) + bA.w, 0.f) * wA.w;
    p += fmaxf(fmaf(bflo(vs.z), sii, a[4]) + bB.x, 0.f) * wB.x;
    p += fmaxf(fmaf(bfhi(vs.z), sii, a[5]) + bB.y, 0.f) * wB.y;
    p += fmaxf(fmaf(bflo(vs.w), sii, a[6]) + bB.z, 0.f) * wB.z;
    p += fmaxf(fmaf(bfhi(vs.w), sii, a[7]) + bB.w, 0.f) * wB.w;
#pragma unroll
    for (int off = 8; off >= 1; off >>= 1) p += __shfl_xor(p, off, 64);
    if (tl == 0) z[i] = p;  // b2 added in agg2
}

// ---------------- agg2: 6-edge batches, 6 scalar gathers in flight ----------------

__global__ __launch_bounds__(256) void k_agg2(const float* __restrict__ zin,
                                              const float* __restrict__ dinv,
                                              const int* __restrict__ rp,
                                              const int* __restrict__ cnt,
                                              const int2* __restrict__ csrw,
                                              const float* __restrict__ b2,
                                              float* __restrict__ out) {
    int i = blockIdx.x * blockDim.x + threadIdx.x;
    if (i >= N_NODES) return;
    float di = dinv[i];
    int beg = rp[i], end = beg + cnt[i];
    float acc = 0.f;
    int j = beg;
    if ((j & 1) && j < end) {
        int2 e = csrw[j];
        acc = fmaf(zin[e.x], __int_as_float(e.y), acc);
        ++j;
    }
    for (; j + 6 <= end; j += 6) {
        uint4 m0 = *(const uint4*)(csrw + j);
        uint4 m1 = *(const uint4*)(csrw + j + 2);
        uint4 m2 = *(const uint4*)(csrw + j + 4);
        float z0 = zin[(int)m0.x], z1 = zin[(int)m0.z];
        float z2 = zin[(int)m1.x], z3 = zin[(int)m1.z];
        float z4 = zin[(int)m2.x], z5 = zin[(int)m2.z];
        acc = fmaf(z0, __int_as_float(m0.y), acc);
        acc = fmaf(z1, __int_as_float(m0.w), acc);
        acc = fmaf(z2, __int_as_float(m1.y), acc);
        acc = fmaf(z3, __int_as_float(m1.w), acc);
        acc = fmaf(z4, __int_as_float(m2.y), acc);
        acc = fmaf(z5, __int_as_float(m2.w), acc);
    }
    for (; j < end; ++j) {
        int2 e = csrw[j];
        acc = fmaf(zin[e.x], __int_as_float(e.y), acc);
    }
    out[i] = acc + zin[i] * di * di + b2[0];
}

// ---------------- launch ----------------

extern "C" void kernel_launch(void* const* d_in, const int* in_sizes, int n_in,
                              void* d_out, int out_size, void* d_ws, size_t ws_size,
                              hipStream_t stream) {
    const float* x  = (const float*)d_in[0];
    const int*   ei = (const int*)d_in[1];
    const float* W1 = (const float*)d_in[2];
    const float* b1 = (const float*)d_in[3];
    const float* W2 = (const float*)d_in[4];
    const float* b2 = (const float*)d_in[5];
    float* out = (float*)d_out;

    const int* src = ei;
    const int* dst = ei + N_EDGES;

    char* ws = (char*)d_ws;
    size_t o = 0;
    auto take = [&](size_t bytes) { char* p = ws + o; o += (bytes + 255) & ~(size_t)255; return p; };
    int*   cnt   = (int*)take(sizeof(int) * N_NODES);
    int*   rp    = (int*)take(sizeof(int) * N_NODES);
    int*   gcur  = (int*)take(sizeof(int) * (NBUCK + 1));
    float* dinv  = (float*)take(sizeof(float) * N_NODES);
    float* z     = (float*)take(sizeof(float) * N_NODES);
    int2*  csrw  = (int2*)take(sizeof(int2) * (size_t)NBUCK * BCAP);
    unsigned short* h1 = (unsigned short*)take(sizeof(unsigned short) * (size_t)N_NODES * DIM);
    int2* ebuf_sep = (int2*)take(sizeof(int2) * (size_t)NBUCK * BCAP);
    bool fused = (o <= ws_size);
    int2* ebuf = fused ? ebuf_sep : (int2*)h1;  // fallback: alias h1 (lifetimes disjoint)

    const int NB_N = (N_NODES + 255) / 256;

    k_zero<<<2, 256, 0, stream>>>(gcur);
    if (fused) {
        k_pg<<<NB_PART + GGRID, 256, 0, stream>>>(src, dst, gcur, ebuf, x, W1, h1);
        k_csrA<<<NBUCK, 256, 0, stream>>>(ebuf, gcur, rp, cnt, dinv);
        k_csrB<<<NBUCK, 256, 0, stream>>>(ebuf, gcur, rp, dinv, csrw);
    } else {
        k_part<<<NB_PART, 256, 0, stream>>>(src, dst, gcur, ebuf);
        k_csrA<<<NBUCK, 256, 0, stream>>>(ebuf, gcur, rp, cnt, dinv);
        k_csrB<<<NBUCK, 256, 0, stream>>>(ebuf, gcur, rp, dinv, csrw);
        k_gemm<<<GGRID, 256, 0, stream>>>(x, W1, h1);  // after last ebuf read
    }
    k_agg1<<<N_NODES / 16, 256, 0, stream>>>(h1, dinv, rp, cnt, csrw, b1, W2, z);
    k_agg2<<<NB_N, 256, 0, stream>>>(z, dinv, rp, cnt, csrw, b2, out);
}

// Round 9
// 147.742 us; speedup vs baseline: 1.0099x; 1.0099x over previous
//
#include <hip/hip_runtime.h>

#define N_NODES 100000
#define N_EDGES 1600000
#define DIM 128

#define BSHIFT 8
#define BNODES 256
#define NBUCK 391     // ceil(100000/256)
#define BCAP  4608    // padded bucket capacity (mean 4096, sigma 64, +8 sigma)
#define PCHUNK 4096   // edges per part block
#define NB_PART ((N_EDGES + PCHUNK - 1) / PCHUNK)  // 391

#define NSEG 25       // src segments of 4096 nodes (1 MB of h1 each)
#define SEGSHIFT 12

#define GTILES 1563   // ceil(100000/64)
#define GGRID  782

typedef short s16x8 __attribute__((ext_vector_type(8)));
typedef float f32x4 __attribute__((ext_vector_type(4)));

__device__ __forceinline__ unsigned short f2bf(float f) {
    unsigned u = __float_as_uint(f);
    u += 0x7fffu + ((u >> 16) & 1u);   // RNE
    return (unsigned short)(u >> 16);
}
__device__ __forceinline__ float bflo(unsigned u) { return __uint_as_float(u << 16); }
__device__ __forceinline__ float bfhi(unsigned u) { return __uint_as_float(u & 0xffff0000u); }

// ---------------- CSR build (padded buckets) ----------------

__global__ void k_zero(int* __restrict__ gcur) {
    int t = blockIdx.x * blockDim.x + threadIdx.x;
    if (t < NBUCK) gcur[t] = t * BCAP;
}

// ---- partition body ----
__device__ __forceinline__ void part_body(char* smem, int bid,
                                          const int* __restrict__ src,
                                          const int* __restrict__ dst,
                                          int* __restrict__ gcur,
                                          int2* __restrict__ ebuf) {
    int* hist = (int*)smem;
    int* gbase = hist + NBUCK;
    int tid = threadIdx.x;
    long e0 = (long)bid * PCHUNK;
    int n = min(PCHUNK, (int)(N_EDGES - e0));
    for (int b = tid; b < NBUCK; b += 256) hist[b] = 0;
    __syncthreads();

    int mys[16], myd[16];
#pragma unroll
    for (int k = 0; k < 16; ++k) {
        int idx = k * 256 + tid;
        if (idx < n) {
            mys[k] = src[e0 + idx];
            myd[k] = dst[e0 + idx];
            atomicAdd(&hist[myd[k] >> BSHIFT], 1);
        } else {
            myd[k] = -1;
        }
    }
    __syncthreads();
    for (int b = tid; b < NBUCK; b += 256) {
        gbase[b] = hist[b] ? atomicAdd(&gcur[b], hist[b]) : 0;
        hist[b] = 0;  // becomes local cursor
    }
    __syncthreads();
#pragma unroll
    for (int k = 0; k < 16; ++k) {
        if (myd[k] >= 0) {
            int b = myd[k] >> BSHIFT;
            int slot = gbase[b] + atomicAdd(&hist[b], 1);
            ebuf[slot] = make_int2(mys[k], myd[k]);
        }
    }
}

// ---- GEMM body: h1(bf16) = x @ W1, bf16 MFMA, swizzled LDS ----
__device__ __forceinline__ void gemm_body(char* smem, int bid,
                                          const float* __restrict__ x,
                                          const float* __restrict__ W1,
                                          unsigned short* __restrict__ h1) {
    unsigned short* Wt = (unsigned short*)smem;           // 32 KB
    int tid = threadIdx.x;
    for (int idx = tid; idx < DIM * DIM; idx += 256) {
        int k = idx >> 7, c = idx & 127;
        Wt[c * 128 + (k ^ ((c & 7) << 3))] = f2bf(W1[idx]);
    }
    __syncthreads();

    int wv = tid >> 6, lane = tid & 63;
    int g = lane >> 4, tl = lane & 15;
    unsigned short* cst = (unsigned short*)(smem + 32768 + wv * 4096);

    for (int tile = bid; tile < GTILES; tile += GGRID) {
        int rb = tile * 64 + wv * 16;
        if (rb >= N_NODES) continue;

        s16x8 afrag[4];
        const float* xrow = x + (size_t)(rb + tl) * DIM + g * 8;
#pragma unroll
        for (int kc = 0; kc < 4; ++kc) {
            float4 p0 = *(const float4*)(xrow + kc * 32);
            float4 p1 = *(const float4*)(xrow + kc * 32 + 4);
            s16x8 a;
            a[0] = (short)f2bf(p0.x); a[1] = (short)f2bf(p0.y);
            a[2] = (short)f2bf(p0.z); a[3] = (short)f2bf(p0.w);
            a[4] = (short)f2bf(p1.x); a[5] = (short)f2bf(p1.y);
            a[6] = (short)f2bf(p1.z); a[7] = (short)f2bf(p1.w);
            afrag[kc] = a;
        }

        f32x4 acc[8];
#pragma unroll
        for (int ct = 0; ct < 8; ++ct) acc[ct] = (f32x4)0.0f;
#pragma unroll
        for (int kc = 0; kc < 4; ++kc) {
#pragma unroll
            for (int ct = 0; ct < 8; ++ct) {
                int crow = ct * 16 + tl;
                int boff = crow * 256 + ((kc * 64 + g * 16) ^ ((crow & 7) << 4));
                s16x8 b = *(const s16x8*)((const char*)Wt + boff);
                acc[ct] = __builtin_amdgcn_mfma_f32_16x16x32_bf16(afrag[kc], b, acc[ct], 0, 0, 0);
            }
        }

#pragma unroll
        for (int ct = 0; ct < 8; ++ct) {
#pragma unroll
            for (int r = 0; r < 4; ++r) {
                float own = acc[ct][r];
                float oth = __shfl_xor(own, 1, 64);
                if ((lane & 1) == 0) {
                    unsigned pk = (unsigned)f2bf(own) | ((unsigned)f2bf(oth) << 16);
                    int row = g * 4 + r;
                    int col = ct * 16 + tl;
                    *(unsigned*)&cst[row * 128 + (col ^ (row << 3))] = pk;
                }
            }
        }
        asm volatile("s_waitcnt lgkmcnt(0)" ::: "memory");

        unsigned short* dstp = h1 + (size_t)rb * DIM;
#pragma unroll
        for (int c = 0; c < 4; ++c) {
            int row = c * 4 + g;
            uint4 v = *(const uint4*)&cst[row * 128 + ((tl ^ row) * 8)];
            *(uint4*)(dstp + c * 512 + lane * 8) = v;
        }
    }
}

// standalone kernels (fallback path when ws is tight)
__global__ __launch_bounds__(256) void k_part(const int* __restrict__ src,
                                              const int* __restrict__ dst,
                                              int* __restrict__ gcur,
                                              int2* __restrict__ ebuf) {
    __shared__ __align__(16) char smem[2 * NBUCK * 4 + 16];
    part_body(smem, blockIdx.x, src, dst, gcur, ebuf);
}

__global__ __launch_bounds__(256) void k_gemm(const float* __restrict__ x,
                                              const float* __restrict__ W1,
                                              unsigned short* __restrict__ h1) {
    __shared__ __align__(16) char smem[49152];
    gemm_body(smem, blockIdx.x, x, W1, h1);
}

// fused: blocks [0,NB_PART) partition edges, rest do the GEMM
__global__ __launch_bounds__(256) void k_pg(const int* __restrict__ src,
                                            const int* __restrict__ dst,
                                            int* __restrict__ gcur,
                                            int2* __restrict__ ebuf,
                                            const float* __restrict__ x,
                                            const float* __restrict__ W1,
                                            unsigned short* __restrict__ h1) {
    __shared__ __align__(16) char smem[49152];
    if (blockIdx.x < NB_PART) part_body(smem, blockIdx.x, src, dst, gcur, ebuf);
    else                      gemm_body(smem, blockIdx.x - NB_PART, x, W1, h1);
}

// per-bucket degree count + scan -> rp, cnt, dinv (256 nodes/block)
__global__ __launch_bounds__(256) void k_csrA(const int2* __restrict__ ebuf,
                                              const int* __restrict__ gcur,
                                              int* __restrict__ rp,
                                              int* __restrict__ cnt,
                                              float* __restrict__ dinv) {
    __shared__ int lcnt[BNODES];
    __shared__ int psum[BNODES];
    int b = blockIdx.x, t = threadIdx.x;
    int node0 = b << BSHIFT;
    lcnt[t] = 0;
    __syncthreads();
    int base = b * BCAP, end = gcur[b];
    for (int e = base + t; e < end; e += 256)
        atomicAdd(&lcnt[ebuf[e].y - node0], 1);
    __syncthreads();
    int c = lcnt[t];
    psum[t] = c;
    __syncthreads();
    for (int s = 1; s < 256; s <<= 1) {
        int u = (t >= s) ? psum[t - s] : 0;
        __syncthreads();
        psum[t] += u;
        __syncthreads();
    }
    int node = node0 + t;
    if (node < N_NODES) {
        rp[node] = base + psum[t] - c;
        cnt[node] = c;
        dinv[node] = rsqrtf((float)(c + 1));
    }
}

// per-bucket CSR emit, counting-sorted by (node, src-segment):
// per-dst adjacency becomes src-segment-ordered -> agg1's gathers sweep
// h1 in ~1MB windows, L2-resident across all concurrently-running waves.
__global__ __launch_bounds__(256) void k_csrB(const int2* __restrict__ ebuf,
                                              const int* __restrict__ gcur,
                                              const int* __restrict__ rp,
                                              const float* __restrict__ dinv,
                                              int2* __restrict__ csrw) {
    __shared__ int lcnt[BNODES * NSEG];   // 25.6 KB: per-(node,seg) count -> cursor
    __shared__ float ldv[BNODES];
    int b = blockIdx.x, t = threadIdx.x;
    int node0 = b << BSHIFT;
    int base = b * BCAP, end = gcur[b];
    int node = node0 + t;
    if (node < N_NODES) ldv[t] = dinv[node];
    for (int k = t; k < BNODES * NSEG; k += 256) lcnt[k] = 0;
    __syncthreads();
    // pass A: count per (node, seg)
    for (int e = base + t; e < end; e += 256) {
        int2 d = ebuf[e];
        atomicAdd(&lcnt[(d.y - node0) * NSEG + (d.x >> SEGSHIFT)], 1);
    }
    __syncthreads();
    // per-node exclusive prefix over segs -> cursor starts (stride 25, bank-clean)
    {
        int run = (node < N_NODES) ? (rp[node] - base) : 0;
        int* row = &lcnt[t * NSEG];
#pragma unroll
        for (int s = 0; s < NSEG; ++s) {
            int c = row[s];
            row[s] = run;
            run += c;
        }
    }
    __syncthreads();
    // pass B: emit seg-sorted per-node lists
    for (int e = base + t; e < end; e += 256) {
        int2 d = ebuf[e];
        int l = d.y - node0;
        float w = dinv[d.x] * ldv[l];
        int p = atomicAdd(&lcnt[l * NSEG + (d.x >> SEGSHIFT)], 1);
        csrw[base + p] = make_int2(d.x, __float_as_int(w));
    }
}

// ---------------- agg1 + b1 + ReLU + (r @ W2) -> z[N] ----------------
// 16-lane group per node; unroll x4 (R7 form — best measured)

__global__ __launch_bounds__(256) void k_agg1(const unsigned short* __restrict__ h1,
                                              const float* __restrict__ dinv,
                                              const int* __restrict__ rp,
                                              const int* __restrict__ cnt,
                                              const int2* __restrict__ csrw,
                                              const float* __restrict__ b1,
                                              const float* __restrict__ W2,
                                              float* __restrict__ z) {
    int lane = threadIdx.x & 63;
    int wv = threadIdx.x >> 6;
    int g = lane >> 4, tl = lane & 15;
    int i = blockIdx.x * 16 + wv * 4 + g;
    int c0 = tl * 8;
    float di = dinv[i];
    int beg = rp[i], end = beg + cnt[i];
    float a0 = 0.f, a1 = 0.f, a2 = 0.f, a3 = 0.f, a4 = 0.f, a5 = 0.f, a6 = 0.f, a7 = 0.f;
    const unsigned short* hbase = h1 + c0;

    int j = beg;
    for (; j + 4 <= end; j += 4) {
        int2 e0 = csrw[j];
        int2 e1 = csrw[j + 1];
        int2 e2 = csrw[j + 2];
        int2 e3 = csrw[j + 3];
        uint4 v0 = *(const uint4*)(hbase + (size_t)e0.x * DIM);
        uint4 v1 = *(const uint4*)(hbase + (size_t)e1.x * DIM);
        uint4 v2 = *(const uint4*)(hbase + (size_t)e2.x * DIM);
        uint4 v3 = *(const uint4*)(hbase + (size_t)e3.x * DIM);
        float w0 = __int_as_float(e0.y), w1 = __int_as_float(e1.y);
        float w2 = __int_as_float(e2.y), w3 = __int_as_float(e3.y);
        a0 = fmaf(bflo(v0.x), w0, a0); a1 = fmaf(bfhi(v0.x), w0, a1);
        a2 = fmaf(bflo(v0.y), w0, a2); a3 = fmaf(bfhi(v0.y), w0, a3);
        a4 = fmaf(bflo(v0.z), w0, a4); a5 = fmaf(bfhi(v0.z), w0, a5);
        a6 = fmaf(bflo(v0.w), w0, a6); a7 = fmaf(bfhi(v0.w), w0, a7);
        a0 = fmaf(bflo(v1.x), w1, a0); a1 = fmaf(bfhi(v1.x), w1, a1);
        a2 = fmaf(bflo(v1.y), w1, a2); a3 = fmaf(bfhi(v1.y), w1, a3);
        a4 = fmaf(bflo(v1.z), w1, a4); a5 = fmaf(bfhi(v1.z), w1, a5);
        a6 = fmaf(bflo(v1.w), w1, a6); a7 = fmaf(bfhi(v1.w), w1, a7);
        a0 = fmaf(bflo(v2.x), w2, a0); a1 = fmaf(bfhi(v2.x), w2, a1);
        a2 = fmaf(bflo(v2.y), w2, a2); a3 = fmaf(bfhi(v2.y), w2, a3);
        a4 = fmaf(bflo(v2.z), w2, a4); a5 = fmaf(bfhi(v2.z), w2, a5);
        a6 = fmaf(bflo(v2.w), w2, a6); a7 = fmaf(bfhi(v2.w), w2, a7);
        a0 = fmaf(bflo(v3.x), w3, a0); a1 = fmaf(bfhi(v3.x), w3, a1);
        a2 = fmaf(bflo(v3.y), w3, a2); a3 = fmaf(bfhi(v3.y), w3, a3);
        a4 = fmaf(bflo(v3.z), w3, a4); a5 = fmaf(bfhi(v3.z), w3, a5);
        a6 = fmaf(bflo(v3.w), w3, a6); a7 = fmaf(bfhi(v3.w), w3, a7);
    }
    for (; j < end; ++j) {
        int2 e0 = csrw[j];
        uint4 v0 = *(const uint4*)(hbase + (size_t)e0.x * DIM);
        float w0 = __int_as_float(e0.y);
        a0 = fmaf(bflo(v0.x), w0, a0); a1 = fmaf(bfhi(v0.x), w0, a1);
        a2 = fmaf(bflo(v0.y), w0, a2); a3 = fmaf(bfhi(v0.y), w0, a3);
        a4 = fmaf(bflo(v0.z), w0, a4); a5 = fmaf(bfhi(v0.z), w0, a5);
        a6 = fmaf(bflo(v0.w), w0, a6); a7 = fmaf(bfhi(v0.w), w0, a7);
    }

    uint4 vs = *(const uint4*)(hbase + (size_t)i * DIM);
    float sii = di * di;
    float4 bA = *(const float4*)(b1 + c0);
    float4 bB = *(const float4*)(b1 + c0 + 4);
    float4 wA = *(const float4*)(W2 + c0);
    float4 wB = *(const float4*)(W2 + c0 + 4);
    float p = 0.f;
    p += fmaxf(fmaf(bflo(vs.x), sii, a0) + bA.x, 0.f) * wA.x;
    p += fmaxf(fmaf(bfhi(vs.x), sii, a1) + bA.y, 0.f) * wA.y;
    p += fmaxf(fmaf(bflo(vs.y), sii, a2) + bA.z, 0.f) * wA.z;
    p += fmaxf(fmaf(bfhi(vs.y), sii, a3) + bA.w, 0.f) * wA.w;
    p += fmaxf(fmaf(bflo(vs.z), sii, a4) + bB.x, 0.f) * wB.x;
    p += fmaxf(fmaf(bfhi(vs.z), sii, a5) + bB.y, 0.f) * wB.y;
    p += fmaxf(fmaf(bflo(vs.w), sii, a6) + bB.z, 0.f) * wB.z;
    p += fmaxf(fmaf(bfhi(vs.w), sii, a7) + bB.w, 0.f) * wB.w;
#pragma unroll
    for (int off = 8; off >= 1; off >>= 1) p += __shfl_xor(p, off, 64);
    if (tl == 0) z[i] = p;  // b2 added in agg2
}

// ---------------- agg2 (R7 form) ----------------

__global__ __launch_bounds__(256) void k_agg2(const float* __restrict__ zin,
                                              const float* __restrict__ dinv,
                                              const int* __restrict__ rp,
                                              const int* __restrict__ cnt,
                                              const int2* __restrict__ csrw,
                                              const float* __restrict__ b2,
                                              float* __restrict__ out) {
    int i = blockIdx.x * blockDim.x + threadIdx.x;
    if (i >= N_NODES) return;
    float di = dinv[i];
    int beg = rp[i], end = beg + cnt[i];
    float acc = 0.f;
    int j = beg;
    for (; j + 4 <= end; j += 4) {
        int2 e0 = csrw[j], e1 = csrw[j + 1], e2 = csrw[j + 2], e3 = csrw[j + 3];
        float z0 = zin[e0.x], z1 = zin[e1.x], z2 = zin[e2.x], z3 = zin[e3.x];
        acc = fmaf(z0, __int_as_float(e0.y), acc);
        acc = fmaf(z1, __int_as_float(e1.y), acc);
        acc = fmaf(z2, __int_as_float(e2.y), acc);
        acc = fmaf(z3, __int_as_float(e3.y), acc);
    }
    for (; j < end; ++j) {
        int2 e = csrw[j];
        acc = fmaf(zin[e.x], __int_as_float(e.y), acc);
    }
    out[i] = acc + zin[i] * di * di + b2[0];
}

// ---------------- launch ----------------

extern "C" void kernel_launch(void* const* d_in, const int* in_sizes, int n_in,
                              void* d_out, int out_size, void* d_ws, size_t ws_size,
                              hipStream_t stream) {
    const float* x  = (const float*)d_in[0];
    const int*   ei = (const int*)d_in[1];
    const float* W1 = (const float*)d_in[2];
    const float* b1 = (const float*)d_in[3];
    const float* W2 = (const float*)d_in[4];
    const float* b2 = (const float*)d_in[5];
    float* out = (float*)d_out;

    const int* src = ei;
    const int* dst = ei + N_EDGES;

    char* ws = (char*)d_ws;
    size_t o = 0;
    auto take = [&](size_t bytes) { char* p = ws + o; o += (bytes + 255) & ~(size_t)255; return p; };
    int*   cnt   = (int*)take(sizeof(int) * N_NODES);
    int*   rp    = (int*)take(sizeof(int) * N_NODES);
    int*   gcur  = (int*)take(sizeof(int) * (NBUCK + 1));
    float* dinv  = (float*)take(sizeof(float) * N_NODES);
    float* z     = (float*)take(sizeof(float) * N_NODES);
    int2*  csrw  = (int2*)take(sizeof(int2) * (size_t)NBUCK * BCAP);
    unsigned short* h1 = (unsigned short*)take(sizeof(unsigned short) * (size_t)N_NODES * DIM);
    int2* ebuf_sep = (int2*)take(sizeof(int2) * (size_t)NBUCK * BCAP);
    bool fused = (o <= ws_size);
    int2* ebuf = fused ? ebuf_sep : (int2*)h1;  // fallback: alias h1 (lifetimes disjoint)

    const int NB_N = (N_NODES + 255) / 256;

    k_zero<<<2, 256, 0, stream>>>(gcur);
    if (fused) {
        k_pg<<<NB_PART + GGRID, 256, 0, stream>>>(src, dst, gcur, ebuf, x, W1, h1);
        k_csrA<<<NBUCK, 256, 0, stream>>>(ebuf, gcur, rp, cnt, dinv);
        k_csrB<<<NBUCK, 256, 0, stream>>>(ebuf, gcur, rp, dinv, csrw);
    } else {
        k_part<<<NB_PART, 256, 0, stream>>>(src, dst, gcur, ebuf);
        k_csrA<<<NBUCK, 256, 0, stream>>>(ebuf, gcur, rp, cnt, dinv);
        k_csrB<<<NBUCK, 256, 0, stream>>>(ebuf, gcur, rp, dinv, csrw);
        k_gemm<<<GGRID, 256, 0, stream>>>(x, W1, h1);  // after last ebuf read
    }
    k_agg1<<<N_NODES / 16, 256, 0, stream>>>(h1, dinv, rp, cnt, csrw, b1, W2, z);
    k_agg2<<<NB_N, 256, 0, stream>>>(z, dinv, rp, cnt, csrw, b2, out);
}